// Round 1
// baseline (312.952 us; speedup 1.0000x reference)
//
#include <hip/hip_runtime.h>
#include <cstdint>

// Problem constants (fixed by setup_inputs)
#define B_   4
#define N_   50000
#define K_   27
#define P_   (B_ * N_)          // 200000 points
#define L_   (P_ * K_)          // 5400000 flat entries
#define S_   130                // per-dim encoding stride
#define KS_  (B_ * S_ * S_ * S_)// 8788000 possible keys

#define SCAN_BLOCK 256
#define SCAN_ITEMS 4
#define SCAN_TILE  (SCAN_BLOCK * SCAN_ITEMS)     // 1024
#define NB1        ((L_ + SCAN_TILE - 1) / SCAN_TILE) // 5274

__device__ __forceinline__ int key_of(int l, const int* __restrict__ coords,
                                      const int* __restrict__ bidx,
                                      const int* __restrict__ koffs) {
    int p = l / K_;
    int k = l - p * K_;
    int key = bidx[p];
    #pragma unroll
    for (int d = 0; d < 3; ++d) {
        int c = coords[p * 3 + d] + koffs[k * 3 + d] + 1;  // +PAD
        key = key * S_ + c;
    }
    return key;
}

__global__ __launch_bounds__(256) void k_init_table(int* __restrict__ T) {
    int i = blockIdx.x * blockDim.x + threadIdx.x;
    if (i < KS_) T[i] = 0x7fffffff;
}

// input_idx = n, rel_pos_idx = k, output_key_tensor pre-filled with -1
__global__ __launch_bounds__(256) void k_fill_outputs(int* __restrict__ out0,
                                                      int* __restrict__ out2,
                                                      int* __restrict__ outkey) {
    int i = blockIdx.x * blockDim.x + threadIdx.x;
    if (i < 3 * L_) outkey[i] = -1;
    if (i < L_) {
        int p = i / K_;
        int k = i - p * K_;
        out0[i] = p % N_;   // n
        out2[i] = k;
    }
}

__global__ __launch_bounds__(256) void k_first_occ(const int* __restrict__ coords,
                                                   const int* __restrict__ bidx,
                                                   const int* __restrict__ koffs,
                                                   int* __restrict__ T) {
    int l = blockIdx.x * blockDim.x + threadIdx.x;
    if (l >= L_) return;
    int key = key_of(l, coords, bidx, koffs);
    atomicMin(&T[key], l);
}

// flags + per-block exclusive scan; prefix lives in the output_idx region of d_out
__global__ __launch_bounds__(SCAN_BLOCK) void k_scan_local(const int* __restrict__ coords,
                                                           const int* __restrict__ bidx,
                                                           const int* __restrict__ koffs,
                                                           const int* __restrict__ T,
                                                           int* __restrict__ prefix,
                                                           int* __restrict__ blockSums) {
    __shared__ int sh[SCAN_BLOCK];
    int base = blockIdx.x * SCAN_TILE + threadIdx.x * SCAN_ITEMS;
    int f[SCAN_ITEMS];
    int s = 0;
    #pragma unroll
    for (int j = 0; j < SCAN_ITEMS; ++j) {
        int l = base + j;
        int fl = 0;
        if (l < L_) {
            int key = key_of(l, coords, bidx, koffs);
            fl = (T[key] == l) ? 1 : 0;
        }
        f[j] = fl;
        s += fl;
    }
    sh[threadIdx.x] = s;
    __syncthreads();
    for (int off = 1; off < SCAN_BLOCK; off <<= 1) {
        int t = (threadIdx.x >= off) ? sh[threadIdx.x - off] : 0;
        __syncthreads();
        sh[threadIdx.x] += t;
        __syncthreads();
    }
    int incl = sh[threadIdx.x];
    int run = incl - s;                  // exclusive prefix for this thread
    #pragma unroll
    for (int j = 0; j < SCAN_ITEMS; ++j) {
        int l = base + j;
        if (l < L_) prefix[l] = run;
        run += f[j];
    }
    if (threadIdx.x == SCAN_BLOCK - 1) blockSums[blockIdx.x] = sh[SCAN_BLOCK - 1];
}

// single-block exclusive scan over block sums; also emits num_unique
__global__ __launch_bounds__(SCAN_BLOCK) void k_scan_sums(int* __restrict__ blockSums,
                                                          int* __restrict__ num_unique_out) {
    __shared__ int sh[SCAN_BLOCK];
    int carry = 0;
    for (int baseI = 0; baseI < NB1; baseI += SCAN_BLOCK) {
        int i = baseI + threadIdx.x;
        int v = (i < NB1) ? blockSums[i] : 0;
        sh[threadIdx.x] = v;
        __syncthreads();
        for (int off = 1; off < SCAN_BLOCK; off <<= 1) {
            int t = (threadIdx.x >= off) ? sh[threadIdx.x - off] : 0;
            __syncthreads();
            sh[threadIdx.x] += t;
            __syncthreads();
        }
        int incl = sh[threadIdx.x];
        if (i < NB1) blockSums[i] = carry + incl - v;   // global exclusive prefix
        int total = sh[SCAN_BLOCK - 1];
        __syncthreads();   // protect sh before next tile
        carry += total;
    }
    if (threadIdx.x == 0) num_unique_out[0] = carry;
}

__global__ __launch_bounds__(SCAN_BLOCK) void k_scan_add(int* __restrict__ prefix,
                                                         const int* __restrict__ blockSums) {
    int off = blockSums[blockIdx.x];
    int base = blockIdx.x * SCAN_TILE;
    #pragma unroll
    for (int j = 0; j < SCAN_ITEMS; ++j) {
        int l = base + j * SCAN_BLOCK + threadIdx.x;
        if (l < L_) prefix[l] += off;
    }
}

// first-occ threads: write decoded unique key at row=rank, store -(rank+1) in table.
// Safe vs. concurrent readers: table values seen are either first-occ flat idx (>=0,
// != other l) or negative -> the `== l` test never false-positives.
__global__ __launch_bounds__(256) void k_emit_unique(const int* __restrict__ coords,
                                                     const int* __restrict__ bidx,
                                                     const int* __restrict__ koffs,
                                                     int* __restrict__ T,
                                                     const int* __restrict__ prefix,
                                                     int* __restrict__ outkey) {
    int l = blockIdx.x * blockDim.x + threadIdx.x;
    if (l >= L_) return;
    int key = key_of(l, coords, bidx, koffs);
    if (T[key] == l) {
        int r = prefix[l];
        int e = key;
        int z = e % S_ - 1; e /= S_;
        int y = e % S_ - 1; e /= S_;
        int x = e % S_ - 1;
        outkey[r * 3 + 0] = x;
        outkey[r * 3 + 1] = y;
        outkey[r * 3 + 2] = z;
        T[key] = -(r + 1);
    }
}

__global__ __launch_bounds__(256) void k_output_idx(const int* __restrict__ coords,
                                                    const int* __restrict__ bidx,
                                                    const int* __restrict__ koffs,
                                                    const int* __restrict__ T,
                                                    int* __restrict__ out1) {
    int l = blockIdx.x * blockDim.x + threadIdx.x;
    if (l >= L_) return;
    int key = key_of(l, coords, bidx, koffs);
    out1[l] = -T[key] - 1;
}

extern "C" void kernel_launch(void* const* d_in, const int* in_sizes, int n_in,
                              void* d_out, int out_size, void* d_ws, size_t ws_size,
                              hipStream_t stream) {
    const int* coords = (const int*)d_in[0];   // [B,N,3] int32
    const int* bidx   = (const int*)d_in[1];   // [B,N]   int32
    const int* koffs  = (const int*)d_in[2];   // [27,3]  int32

    int* out      = (int*)d_out;
    int* out0     = out;            // input_idx      [L]
    int* out1     = out + L_;       // output_idx     [L] (prefix scratch first)
    int* out2     = out + 2 * L_;   // rel_pos_idx    [L]
    int* outkey   = out + 3 * L_;   // output_key     [L,3]
    int* numuniq  = out + 6 * L_;   // num_unique     [1]

    int* T         = (int*)d_ws;    // KS_ ints (35.2 MB)
    int* blockSums = T + KS_;       // NB1 ints

    k_init_table  <<<(KS_ + 255) / 256, 256, 0, stream>>>(T);
    k_fill_outputs<<<(3 * L_ + 255) / 256, 256, 0, stream>>>(out0, out2, outkey);
    k_first_occ   <<<(L_ + 255) / 256, 256, 0, stream>>>(coords, bidx, koffs, T);
    k_scan_local  <<<NB1, SCAN_BLOCK, 0, stream>>>(coords, bidx, koffs, T, out1, blockSums);
    k_scan_sums   <<<1, SCAN_BLOCK, 0, stream>>>(blockSums, numuniq);
    k_scan_add    <<<NB1, SCAN_BLOCK, 0, stream>>>(out1, blockSums);
    k_emit_unique <<<(L_ + 255) / 256, 256, 0, stream>>>(coords, bidx, koffs, T, out1, outkey);
    k_output_idx  <<<(L_ + 255) / 256, 256, 0, stream>>>(coords, bidx, koffs, T, out1);
}

// Round 2
// 240.912 us; speedup vs baseline: 1.2990x; 1.2990x over previous
//
#include <hip/hip_runtime.h>
#include <cstdint>

// Problem constants (fixed by setup_inputs)
#define B_   4
#define N_   50000
#define K_   27
#define P_   (B_ * N_)           // 200000 points
#define L_   (P_ * K_)           // 5400000 flat entries
#define S_   130                 // per-dim encoding stride
#define KS_  (B_ * S_ * S_ * S_) // 8788000 possible keys

#define SB   256
#define SI   4
#define ST   (SB * SI)                    // 1024 items per scan tile
#define NB1  ((L_ + ST - 1) / ST)         // 5274 tiles

__device__ __forceinline__ int key_of(int l, const int* __restrict__ coords,
                                      const int* __restrict__ bidx,
                                      const int* __restrict__ koffs) {
    int p = l / K_;
    int k = l - p * K_;
    int key = bidx[p];
    #pragma unroll
    for (int d = 0; d < 3; ++d) {
        int c = coords[p * 3 + d] + koffs[k * 3 + d] + 1;  // +PAD
        key = key * S_ + c;
    }
    return key;
}

// table init + input_idx / rel_pos_idx fill, one fused grid
__global__ __launch_bounds__(256) void k_init2(int* __restrict__ T,
                                               int* __restrict__ out0,
                                               int* __restrict__ out2) {
    int i = blockIdx.x * blockDim.x + threadIdx.x;
    if (i < KS_) T[i] = 0x7fffffff;
    if (i < L_) {
        int p = i / K_;
        int k = i - p * K_;
        out0[i] = p - (p / N_) * N_;   // n
        out2[i] = k;
    }
}

__global__ __launch_bounds__(256) void k_first_occ(const int* __restrict__ coords,
                                                   const int* __restrict__ bidx,
                                                   const int* __restrict__ koffs,
                                                   int* __restrict__ T) {
    int l = blockIdx.x * blockDim.x + threadIdx.x;
    if (l >= L_) return;
    int key = key_of(l, coords, bidx, koffs);
    atomicMin(&T[key], l);
}

// Pass B: single random table read per l. Stores m (first-occ flat idx) into
// out1 (final output_idx region, overwritten later), flag local-scan into prefA.
__global__ __launch_bounds__(SB) void k_flag_scan(const int* __restrict__ coords,
                                                  const int* __restrict__ bidx,
                                                  const int* __restrict__ koffs,
                                                  const int* __restrict__ T,
                                                  int* __restrict__ mArr,
                                                  int* __restrict__ prefA,
                                                  int* __restrict__ blockSums) {
    __shared__ int sh[SB];
    int base = blockIdx.x * ST + threadIdx.x * SI;
    int f[SI];
    int s = 0;
    #pragma unroll
    for (int j = 0; j < SI; ++j) {
        int l = base + j;
        int fl = 0;
        if (l < L_) {
            int key = key_of(l, coords, bidx, koffs);
            int m = T[key];
            mArr[l] = m;
            fl = (m == l) ? 1 : 0;
        }
        f[j] = fl;
        s += fl;
    }
    sh[threadIdx.x] = s;
    __syncthreads();
    for (int off = 1; off < SB; off <<= 1) {
        int t = (threadIdx.x >= off) ? sh[threadIdx.x - off] : 0;
        __syncthreads();
        sh[threadIdx.x] += t;
        __syncthreads();
    }
    int incl = sh[threadIdx.x];
    int run = incl - s;                  // exclusive prefix for this thread
    #pragma unroll
    for (int j = 0; j < SI; ++j) {
        int l = base + j;
        if (l < L_) prefA[l] = run;
        run += f[j];
    }
    if (threadIdx.x == SB - 1) blockSums[blockIdx.x] = sh[SB - 1];
}

// single-block exclusive scan over block sums; also emits num_unique
__global__ __launch_bounds__(SB) void k_scan_sums(int* __restrict__ blockSums,
                                                  int* __restrict__ num_unique_out) {
    __shared__ int sh[SB];
    int carry = 0;
    for (int baseI = 0; baseI < NB1; baseI += SB) {
        int i = baseI + threadIdx.x;
        int v = (i < NB1) ? blockSums[i] : 0;
        sh[threadIdx.x] = v;
        __syncthreads();
        for (int off = 1; off < SB; off <<= 1) {
            int t = (threadIdx.x >= off) ? sh[threadIdx.x - off] : 0;
            __syncthreads();
            sh[threadIdx.x] += t;
            __syncthreads();
        }
        int incl = sh[threadIdx.x];
        if (i < NB1) blockSums[i] = carry + incl - v;   // global exclusive prefix
        int total = sh[SB - 1];
        __syncthreads();
        carry += total;
    }
    if (threadIdx.x == 0) num_unique_out[0] = carry;
}

// Pass C: fused scan_add + emit + output_idx.
// rank(l) = prefA[m] + blockSums[m>>10]; random read hits 21.6MB prefA only.
__global__ __launch_bounds__(256) void k_finalize(const int* __restrict__ coords,
                                                  const int* __restrict__ koffs,
                                                  const int* __restrict__ prefA,
                                                  const int* __restrict__ blockSums,
                                                  int* __restrict__ out1,   // holds m, becomes output_idx
                                                  int* __restrict__ outkey) {
    int l = blockIdx.x * blockDim.x + threadIdx.x;
    if (l >= L_) return;
    int m = out1[l];
    if (m == l) {
        int r = prefA[l] + blockSums[l >> 10];   // == rank, flag[l]==1
        int p = l / K_;
        int k = l - p * K_;
        outkey[r * 3 + 0] = coords[p * 3 + 0] + koffs[k * 3 + 0];
        outkey[r * 3 + 1] = coords[p * 3 + 1] + koffs[k * 3 + 1];
        outkey[r * 3 + 2] = coords[p * 3 + 2] + koffs[k * 3 + 2];
    }
    int rank = prefA[m] + blockSums[m >> 10];
    out1[l] = rank;
}

// rows beyond num_unique get -1
__global__ __launch_bounds__(256) void k_tail(const int* __restrict__ num_unique,
                                              int* __restrict__ outkey) {
    int r = blockIdx.x * blockDim.x + threadIdx.x;
    if (r >= L_) return;
    if (r >= num_unique[0]) {
        outkey[r * 3 + 0] = -1;
        outkey[r * 3 + 1] = -1;
        outkey[r * 3 + 2] = -1;
    }
}

// ---------------- fallback path (round-1 structure, smaller ws) ----------------

__global__ __launch_bounds__(256) void k_fill_neg1(int* __restrict__ outkey) {
    int i = blockIdx.x * blockDim.x + threadIdx.x;
    if (i < 3 * L_) outkey[i] = -1;
}

__global__ __launch_bounds__(SB) void k_scan_local(const int* __restrict__ coords,
                                                   const int* __restrict__ bidx,
                                                   const int* __restrict__ koffs,
                                                   const int* __restrict__ T,
                                                   int* __restrict__ prefix,
                                                   int* __restrict__ blockSums) {
    __shared__ int sh[SB];
    int base = blockIdx.x * ST + threadIdx.x * SI;
    int f[SI];
    int s = 0;
    #pragma unroll
    for (int j = 0; j < SI; ++j) {
        int l = base + j;
        int fl = 0;
        if (l < L_) {
            int key = key_of(l, coords, bidx, koffs);
            fl = (T[key] == l) ? 1 : 0;
        }
        f[j] = fl;
        s += fl;
    }
    sh[threadIdx.x] = s;
    __syncthreads();
    for (int off = 1; off < SB; off <<= 1) {
        int t = (threadIdx.x >= off) ? sh[threadIdx.x - off] : 0;
        __syncthreads();
        sh[threadIdx.x] += t;
        __syncthreads();
    }
    int incl = sh[threadIdx.x];
    int run = incl - s;
    #pragma unroll
    for (int j = 0; j < SI; ++j) {
        int l = base + j;
        if (l < L_) prefix[l] = run;
        run += f[j];
    }
    if (threadIdx.x == SB - 1) blockSums[blockIdx.x] = sh[SB - 1];
}

__global__ __launch_bounds__(SB) void k_scan_add(int* __restrict__ prefix,
                                                 const int* __restrict__ blockSums) {
    int off = blockSums[blockIdx.x];
    int base = blockIdx.x * ST;
    #pragma unroll
    for (int j = 0; j < SI; ++j) {
        int l = base + j * SB + threadIdx.x;
        if (l < L_) prefix[l] += off;
    }
}

__global__ __launch_bounds__(256) void k_emit_unique(const int* __restrict__ coords,
                                                     const int* __restrict__ bidx,
                                                     const int* __restrict__ koffs,
                                                     int* __restrict__ T,
                                                     const int* __restrict__ prefix,
                                                     int* __restrict__ outkey) {
    int l = blockIdx.x * blockDim.x + threadIdx.x;
    if (l >= L_) return;
    int key = key_of(l, coords, bidx, koffs);
    if (T[key] == l) {
        int r = prefix[l];
        int e = key;
        int z = e % S_ - 1; e /= S_;
        int y = e % S_ - 1; e /= S_;
        int x = e % S_ - 1;
        outkey[r * 3 + 0] = x;
        outkey[r * 3 + 1] = y;
        outkey[r * 3 + 2] = z;
        T[key] = -(r + 1);
    }
}

__global__ __launch_bounds__(256) void k_output_idx(const int* __restrict__ coords,
                                                    const int* __restrict__ bidx,
                                                    const int* __restrict__ koffs,
                                                    const int* __restrict__ T,
                                                    int* __restrict__ out1) {
    int l = blockIdx.x * blockDim.x + threadIdx.x;
    if (l >= L_) return;
    int key = key_of(l, coords, bidx, koffs);
    out1[l] = -T[key] - 1;
}

extern "C" void kernel_launch(void* const* d_in, const int* in_sizes, int n_in,
                              void* d_out, int out_size, void* d_ws, size_t ws_size,
                              hipStream_t stream) {
    const int* coords = (const int*)d_in[0];   // [B,N,3] int32
    const int* bidx   = (const int*)d_in[1];   // [B,N]   int32
    const int* koffs  = (const int*)d_in[2];   // [27,3]  int32

    int* out      = (int*)d_out;
    int* out0     = out;            // input_idx      [L]
    int* out1     = out + L_;       // output_idx     [L] (holds m during fast path)
    int* out2     = out + 2 * L_;   // rel_pos_idx    [L]
    int* outkey   = out + 3 * L_;   // output_key     [L,3]
    int* numuniq  = out + 6 * L_;   // num_unique     [1]

    size_t need_fast = (size_t)(KS_ + L_ + NB1 + 64) * sizeof(int);  // ~57 MB

    if (ws_size >= need_fast) {
        int* T         = (int*)d_ws;       // KS_ ints
        int* prefA     = T + KS_;          // L_ ints
        int* blockSums = prefA + L_;       // NB1 ints

        k_init2     <<<(KS_ + 255) / 256, 256, 0, stream>>>(T, out0, out2);
        k_first_occ <<<(L_ + 255) / 256, 256, 0, stream>>>(coords, bidx, koffs, T);
        k_flag_scan <<<NB1, SB, 0, stream>>>(coords, bidx, koffs, T, out1, prefA, blockSums);
        k_scan_sums <<<1, SB, 0, stream>>>(blockSums, numuniq);
        k_finalize  <<<(L_ + 255) / 256, 256, 0, stream>>>(coords, koffs, prefA, blockSums, out1, outkey);
        k_tail      <<<(L_ + 255) / 256, 256, 0, stream>>>(numuniq, outkey);
    } else {
        // round-1 fallback (needs KS_ + NB1 ints)
        int* T         = (int*)d_ws;
        int* blockSums = T + KS_;

        k_init2      <<<(KS_ + 255) / 256, 256, 0, stream>>>(T, out0, out2);
        k_fill_neg1  <<<(3 * L_ + 255) / 256, 256, 0, stream>>>(outkey);
        k_first_occ  <<<(L_ + 255) / 256, 256, 0, stream>>>(coords, bidx, koffs, T);
        k_scan_local <<<NB1, SB, 0, stream>>>(coords, bidx, koffs, T, out1, blockSums);
        k_scan_sums  <<<1, SB, 0, stream>>>(blockSums, numuniq);
        k_scan_add   <<<NB1, SB, 0, stream>>>(out1, blockSums);
        k_emit_unique<<<(L_ + 255) / 256, 256, 0, stream>>>(coords, bidx, koffs, T, out1, outkey);
        k_output_idx <<<(L_ + 255) / 256, 256, 0, stream>>>(coords, bidx, koffs, T, out1);
    }
}

// Round 3
// 156.944 us; speedup vs baseline: 1.9940x; 1.5350x over previous
//
#include <hip/hip_runtime.h>
#include <cstdint>

// Problem constants (fixed by setup_inputs)
#define B_   4
#define N_   50000
#define K_   27
#define P_   (B_ * N_)           // 200000 points
#define L_   (P_ * K_)           // 5400000 flat entries (divisible by 64)
#define S_   130                 // per-dim encoding stride
#define KS_  (B_ * S_ * S_ * S_) // 8788000 possible keys
#define W_   (L_ / 64)           // 84375 bitmap words
#define NBW  ((W_ + 255) / 256)  // 330 word-scan blocks

__device__ __forceinline__ int key_of(int l, const int* __restrict__ coords,
                                      const int* __restrict__ bidx,
                                      const int* __restrict__ koffs) {
    int p = l / K_;
    int k = l - p * K_;
    int key = bidx[p];
    #pragma unroll
    for (int d = 0; d < 3; ++d) {
        int c = coords[p * 3 + d] + koffs[k * 3 + d] + 1;  // +PAD
        key = key * S_ + c;
    }
    return key;
}

__global__ __launch_bounds__(256) void k_init(int* __restrict__ T) {
    int i = blockIdx.x * blockDim.x + threadIdx.x;
    if (i < KS_) T[i] = 0x7fffffff;
}

// atomicMin first-occurrence pass with all trivial output fills folded in:
// the atomic pipe is the bottleneck here (12% HBM last round), so the
// ~107MB of coalesced writes hide under it.
__global__ __launch_bounds__(256) void k_first_fill(const int* __restrict__ coords,
                                                    const int* __restrict__ bidx,
                                                    const int* __restrict__ koffs,
                                                    int* __restrict__ T,
                                                    int* __restrict__ out0,
                                                    int* __restrict__ out2,
                                                    int* __restrict__ outkey) {
    int l = blockIdx.x * blockDim.x + threadIdx.x;
    if (l >= L_) return;
    int p = l / K_;
    int k = l - p * K_;
    out0[l] = p - (p / N_) * N_;   // n
    out2[l] = k;
    outkey[3 * l + 0] = -1;
    outkey[3 * l + 1] = -1;
    outkey[3 * l + 2] = -1;
    int key = bidx[p];
    #pragma unroll
    for (int d = 0; d < 3; ++d)
        key = key * S_ + (coords[p * 3 + d] + koffs[k * 3 + d] + 1);
    atomicMin(&T[key], l);
}

// One random table read per l; first-occurrence flags -> bitmap via ballot.
__global__ __launch_bounds__(256) void k_flag_bitmap(const int* __restrict__ coords,
                                                     const int* __restrict__ bidx,
                                                     const int* __restrict__ koffs,
                                                     const int* __restrict__ T,
                                                     int* __restrict__ mArr,
                                                     unsigned long long* __restrict__ bitmap) {
    int l = blockIdx.x * blockDim.x + threadIdx.x;
    if (l >= L_) return;
    int key = key_of(l, coords, bidx, koffs);
    int m = T[key];
    mArr[l] = m;
    unsigned long long b = __ballot(m == l);
    if ((threadIdx.x & 63) == 0) bitmap[l >> 6] = b;
}

// Per-word popcount + per-block exclusive scan over 84375 words.
__global__ __launch_bounds__(256) void k_scan_words(const unsigned long long* __restrict__ bitmap,
                                                    int* __restrict__ wpre,
                                                    int* __restrict__ bsum) {
    __shared__ int sh[256];
    int w = blockIdx.x * 256 + threadIdx.x;
    int c = (w < W_) ? __popcll(bitmap[w]) : 0;
    sh[threadIdx.x] = c;
    __syncthreads();
    for (int off = 1; off < 256; off <<= 1) {
        int t = (threadIdx.x >= off) ? sh[threadIdx.x - off] : 0;
        __syncthreads();
        sh[threadIdx.x] += t;
        __syncthreads();
    }
    if (w < W_) wpre[w] = sh[threadIdx.x] - c;        // exclusive within block
    if (threadIdx.x == 255) bsum[blockIdx.x] = sh[255];
}

// Single-block exclusive scan over the 330 block sums; emits num_unique.
__global__ __launch_bounds__(512) void k_scan_block(int* __restrict__ bsum,
                                                    int* __restrict__ num_unique_out) {
    __shared__ int sh[512];
    int i = threadIdx.x;
    int v = (i < NBW) ? bsum[i] : 0;
    sh[i] = v;
    __syncthreads();
    for (int off = 1; off < 512; off <<= 1) {
        int t = (i >= off) ? sh[i - off] : 0;
        __syncthreads();
        sh[i] += t;
        __syncthreads();
    }
    if (i < NBW) bsum[i] = sh[i] - v;                 // global exclusive prefix
    if (i == 0) num_unique_out[0] = sh[511];
}

// rank(m) = wpre[m>>6] + bsum[(m>>6)>>8] + popcount(word & mask). The random
// gather targets bitmap+wpre (~1.3MB, L2-resident). Valid outkey rows are
// written here (rank increases with l for first-occurrences -> near-coalesced).
__global__ __launch_bounds__(256) void k_finalize(const int* __restrict__ coords,
                                                  const int* __restrict__ koffs,
                                                  const unsigned long long* __restrict__ bitmap,
                                                  const int* __restrict__ wpre,
                                                  const int* __restrict__ bsum,
                                                  int* __restrict__ out1,   // holds m, becomes output_idx
                                                  int* __restrict__ outkey) {
    int l = blockIdx.x * blockDim.x + threadIdx.x;
    if (l >= L_) return;
    int m = out1[l];
    int w = m >> 6;
    unsigned long long word = bitmap[w];
    unsigned long long mask = (1ull << (m & 63)) - 1ull;
    int rank = wpre[w] + bsum[w >> 8] + (int)__popcll(word & mask);
    if (m == l) {
        int p = l / K_;
        int k = l - p * K_;
        outkey[3 * rank + 0] = coords[p * 3 + 0] + koffs[k * 3 + 0];
        outkey[3 * rank + 1] = coords[p * 3 + 1] + koffs[k * 3 + 1];
        outkey[3 * rank + 2] = coords[p * 3 + 2] + koffs[k * 3 + 2];
    }
    out1[l] = rank;
}

extern "C" void kernel_launch(void* const* d_in, const int* in_sizes, int n_in,
                              void* d_out, int out_size, void* d_ws, size_t ws_size,
                              hipStream_t stream) {
    const int* coords = (const int*)d_in[0];   // [B,N,3] int32
    const int* bidx   = (const int*)d_in[1];   // [B,N]   int32
    const int* koffs  = (const int*)d_in[2];   // [27,3]  int32

    int* out      = (int*)d_out;
    int* out0     = out;            // input_idx      [L]
    int* out1     = out + L_;       // output_idx     [L] (holds m first)
    int* out2     = out + 2 * L_;   // rel_pos_idx    [L]
    int* outkey   = out + 3 * L_;   // output_key     [L,3]
    int* numuniq  = out + 6 * L_;   // num_unique     [1]

    // ws layout (~36.2 MB): T | bitmap | wpre | bsum
    int* T = (int*)d_ws;                                   // KS_ ints
    unsigned long long* bitmap = (unsigned long long*)(T + KS_);  // W_ u64 (8B-aligned: KS_*4 % 8 == 0)
    int* wpre = (int*)(bitmap + W_);                       // W_ ints
    int* bsum = wpre + W_;                                 // NBW ints

    k_init        <<<(KS_ + 255) / 256, 256, 0, stream>>>(T);
    k_first_fill  <<<(L_ + 255) / 256, 256, 0, stream>>>(coords, bidx, koffs, T, out0, out2, outkey);
    k_flag_bitmap <<<(L_ + 255) / 256, 256, 0, stream>>>(coords, bidx, koffs, T, out1, bitmap);
    k_scan_words  <<<NBW, 256, 0, stream>>>(bitmap, wpre, bsum);
    k_scan_block  <<<1, 512, 0, stream>>>(bsum, numuniq);
    k_finalize    <<<(L_ + 255) / 256, 256, 0, stream>>>(coords, koffs, bitmap, wpre, bsum, out1, outkey);
}